// Round 1
// baseline (889.390 us; speedup 1.0000x reference)
//
#include <hip/hip_runtime.h>
#include <hip/hip_bf16.h>

// SpatiotemporalAttention — fp32 baseline, BN folded into convs, E materialized once.
// B=4, C=256, CI=128, H=W=48, N=2304.
//
// Pipeline:
//  fold_pre  : Wpre_comb[2][256][256] (rows 0..127 = g-branch, 128..255 = theta/phi), bias
//  fold_post : Wpost_eff[2][256][128] (post-BN folded as per-row scale), bias
//  gemm pre  : F1[b]=[256][2304] = Wc[0]@x1[b]+b   (g11 rows 0..127, th1 rows 128..255)
//              F2[b]             = Wc[1]@x2[b]+b   (g21, ph1)
//  e_time    : Et[b][c][d] = sum_n th[c,n] ph[d,n]   (NT gemm, K-split + atomicAdd)
//  et_softmax: M2 = rowsoftmax(Et) (=et1s); M1[c][d] = colsoftmax(Et)[d][c] (=et2s array)
//  A gemms   : A1[b]=M1@g11, A2[b]=M2@g21            [128][2304]
//  E gemm    : E[b][n][m] = sum_c th[c,n] ph[c,m]    (TN gemm, 85 MB in ws)
//  stats     : row (max,1/sum) of E -> y2 path; col stats -> y1 path
//  y gemms   : y1 = A1 @ expcol(E)   (NN, exp fused in B staging)
//              y2 = A2 @ exprow(E)^T (NT, exp fused)
//  post      : out_i = x_i + Wpost[i]@y_i + bias     (NN, residual fused)

#define HW_N   2304
#define NB     4
#define NC     256
#define NCI    128

// ---------------- workspace layout (floats) ----------------
#define OFF_WPRE   0L                      // 2*256*256
#define OFF_BPRE   131072L                 // 512
#define OFF_WPOST  131584L                 // 2*256*128
#define OFF_BPOST  197120L                 // 512
#define OFF_F1     197632L                 // 4*256*2304
#define OFF_F2     2556928L
#define OFF_ET     4916224L                // 4*128*128
#define OFF_M1     4981760L
#define OFF_M2     5047296L
#define OFF_A1     5112832L                // 4*128*2304
#define OFF_A2     6292480L
#define OFF_Y1     7472128L
#define OFF_Y2     8651776L
#define OFF_RMX    9831424L                // 4*2304
#define OFF_RINV   9840640L
#define OFF_CMX    9849856L
#define OFF_CINV   9859072L
#define OFF_ESP    9868288L                // 4*2304*2304
// total 31,101,952 floats = 124.4 MB

__global__ __launch_bounds__(256) void fold_pre(const float* __restrict__ bn,
                                                const float* __restrict__ w,
                                                const float* __restrict__ b,
                                                float* __restrict__ Wc,
                                                float* __restrict__ Bc) {
  int blk = blockIdx.x;            // xsel*256 + row
  int xsel = blk >> 8, row = blk & 255;
  int i = (row < 128) ? xsel : (2 + xsel);   // xsel0:{0,2} xsel1:{1,3}
  int o = row & 127;
  int c = threadIdx.x;             // 256
  const float* bni = bn + i * 4 * 256;
  float g = bni[c], be = bni[256 + c], mn = bni[512 + c], vr = bni[768 + c];
  float s = g * rsqrtf(vr + 1e-5f);
  float t = be - mn * s;
  float wv = w[(i * 128 + o) * 256 + c];
  Wc[(long)(xsel * 256 + row) * 256 + c] = wv * s;
  __shared__ float red[256];
  red[c] = wv * t;
  __syncthreads();
  for (int off = 128; off > 0; off >>= 1) {
    if (c < off) red[c] += red[c + off];
    __syncthreads();
  }
  if (c == 0) Bc[xsel * 256 + row] = b[i * 128 + o] + red[0];
}

__global__ __launch_bounds__(128) void fold_post(const float* __restrict__ bn,
                                                 const float* __restrict__ w,
                                                 const float* __restrict__ b,
                                                 float* __restrict__ Wc,
                                                 float* __restrict__ Bc) {
  int blk = blockIdx.x;            // i*256 + o
  int i = blk >> 8, o = blk & 255;
  const float* bni = bn + i * 4 * 256;
  float s = bni[o] * rsqrtf(bni[768 + o] + 1e-5f);
  int c = threadIdx.x;             // 128
  Wc[(long)(i * 256 + o) * 128 + c] = w[(long)(i * 256 + o) * 128 + c] * s;
  if (c == 0) Bc[i * 256 + o] = b[i * 256 + o] * s + bni[256 + o] - bni[512 + o] * s;
}

// softmaxes of the 128x128 time-energy matrix.
// M2[c][d] = exp(Et[c][d]-rmax_c)/rsum_c          (= et1s)
// M1[c][d] = exp(Et[d][c]-cmax_c)/csum_c          (= et2s as used in einsum)
__global__ __launch_bounds__(128) void et_softmax(const float* __restrict__ Et,
                                                  float* __restrict__ M1,
                                                  float* __restrict__ M2) {
  __shared__ float Es[128 * 128];
  int b = blockIdx.x, t = threadIdx.x;
  const float* E = Et + (long)b * 16384;
  for (int i = t; i < 16384; i += 128) Es[i] = E[i];
  __syncthreads();
  float rm = -1e30f;
  for (int j = 0; j < 128; ++j) rm = fmaxf(rm, Es[t * 128 + j]);
  float rs = 0.f;
  for (int j = 0; j < 128; ++j) rs += __expf(Es[t * 128 + j] - rm);
  float ri = 1.0f / rs;
  for (int j = 0; j < 128; ++j)
    M2[(long)b * 16384 + t * 128 + j] = __expf(Es[t * 128 + j] - rm) * ri;
  float cm = -1e30f;
  for (int d = 0; d < 128; ++d) cm = fmaxf(cm, Es[d * 128 + t]);
  float cs = 0.f;
  for (int d = 0; d < 128; ++d) cs += __expf(Es[d * 128 + t] - cm);
  float ci = 1.0f / cs;
  for (int d = 0; d < 128; ++d)
    M1[(long)b * 16384 + t * 128 + d] = __expf(Es[d * 128 + t] - cm) * ci;
}

// row stats of E: one block per (b,row)
__global__ __launch_bounds__(256) void row_stats(const float* __restrict__ E,
                                                 float* __restrict__ mx,
                                                 float* __restrict__ inv) {
  int b = blockIdx.y, row = blockIdx.x, t = threadIdx.x;
  const float* r = E + ((long)b * HW_N + row) * HW_N;
  float m = -1e30f;
  for (int j = t; j < HW_N; j += 256) m = fmaxf(m, r[j]);
  __shared__ float red[256];
  red[t] = m;
  __syncthreads();
  for (int off = 128; off > 0; off >>= 1) {
    if (t < off) red[t] = fmaxf(red[t], red[t + off]);
    __syncthreads();
  }
  m = red[0];
  __syncthreads();
  float s = 0.f;
  for (int j = t; j < HW_N; j += 256) s += __expf(r[j] - m);
  red[t] = s;
  __syncthreads();
  for (int off = 128; off > 0; off >>= 1) {
    if (t < off) red[t] += red[t + off];
    __syncthreads();
  }
  if (t == 0) { mx[b * HW_N + row] = m; inv[b * HW_N + row] = 1.0f / red[0]; }
}

// col stats of E: block covers 64 columns, 4 threads/column
__global__ __launch_bounds__(256) void col_stats(const float* __restrict__ E,
                                                 float* __restrict__ mx,
                                                 float* __restrict__ inv) {
  int b = blockIdx.y;
  int m = blockIdx.x * 64 + (threadIdx.x & 63);
  int q = threadIdx.x >> 6;
  const float* Eb = E + (long)b * HW_N * HW_N;
  float mm = -1e30f;
  for (int n = q; n < HW_N; n += 4) mm = fmaxf(mm, Eb[(long)n * HW_N + m]);
  float s = 0.f;
  for (int n = q; n < HW_N; n += 4) s += __expf(Eb[(long)n * HW_N + m] - mm);
  __shared__ float rm[256], rs[256];
  rm[threadIdx.x] = mm; rs[threadIdx.x] = s;
  __syncthreads();
  if (q == 0) {
    float m0 = rm[threadIdx.x], m1 = rm[threadIdx.x + 64],
          m2 = rm[threadIdx.x + 128], m3 = rm[threadIdx.x + 192];
    float M = fmaxf(fmaxf(m0, m1), fmaxf(m2, m3));
    float S = rs[threadIdx.x] * __expf(m0 - M) + rs[threadIdx.x + 64] * __expf(m1 - M) +
              rs[threadIdx.x + 128] * __expf(m2 - M) + rs[threadIdx.x + 192] * __expf(m3 - M);
    mx[b * HW_N + m] = M;
    inv[b * HW_N + m] = 1.0f / S;
  }
}

// Generic 64x64-tile fp32 GEMM, 4x4 micro-tile, 256 threads.
//   ATK  : A stored [K][M] (lda = row stride), else [M][K]
//   BT   : B stored [N][K] (row j = output col), else [K][N]
//   EXPB : B elements -> exp(v - mx[col]) * inv[col]   (stats per output column)
//   BIAS : += bias[m];  RESID : += resid[m*ldc+n];  ATOMIC : atomicAdd into C
template <bool ATK, bool BT, bool EXPB, bool BIAS, bool RESID, bool ATOMIC>
__global__ __launch_bounds__(256) void gemm64(
    const float* __restrict__ A, int lda, long sA,
    const float* __restrict__ B, int ldb, long sB,
    float* __restrict__ C, int ldc, long sC,
    int K, int kSplit, int kChunk,
    const float* __restrict__ bias,
    const float* __restrict__ mx, const float* __restrict__ inv, int sStat,
    const float* __restrict__ resid, long sR) {
  int z = blockIdx.z;
  int batch = z / kSplit, ks = z - batch * kSplit;
  int k0 = ks * kChunk, k1 = min(K, k0 + kChunk);
  A += (long)batch * sA;
  B += (long)batch * sB;
  C += (long)batch * sC;
  const float* mxb = EXPB ? mx + (long)batch * sStat : nullptr;
  const float* invb = EXPB ? inv + (long)batch * sStat : nullptr;
  const float* residb = RESID ? resid + (long)batch * sR : nullptr;

  int m0 = blockIdx.y * 64, n0 = blockIdx.x * 64;
  __shared__ float As[16][68];
  __shared__ float Bs[16][68];
  int t = threadIdx.x;
  int tx = t & 15, ty = t >> 4;

  // hoisted softmax stats (staging indices are k-invariant)
  float smN[4], siN[4], smT = 0.f, siT = 0.f;
  if (EXPB) {
    if (!BT) {
      int c4 = (t & 15) << 2;
      #pragma unroll
      for (int i = 0; i < 4; ++i) { smN[i] = mxb[n0 + c4 + i]; siN[i] = invb[n0 + c4 + i]; }
    } else {
      int r = t >> 2;
      smT = mxb[n0 + r];
      siT = invb[n0 + r];
    }
  }

  float acc[4][4] = {};
  for (int kt = k0; kt < k1; kt += 16) {
    __syncthreads();
    // ---- stage A into As[k][m]
    if (ATK) {
      int kk = t >> 4, m4 = (t & 15) << 2;
      float4 a = *(const float4*)&A[(long)(kt + kk) * lda + m0 + m4];
      *(float4*)&As[kk][m4] = a;
    } else {
      int r = t >> 2, c4 = (t & 3) << 2;
      float4 a = *(const float4*)&A[(long)(m0 + r) * lda + kt + c4];
      As[c4 + 0][r] = a.x; As[c4 + 1][r] = a.y; As[c4 + 2][r] = a.z; As[c4 + 3][r] = a.w;
    }
    // ---- stage B into Bs[k][n]
    if (!BT) {
      int kk = t >> 4, c4 = (t & 15) << 2;
      float4 bv = *(const float4*)&B[(long)(kt + kk) * ldb + n0 + c4];
      if (EXPB) {
        bv.x = __expf(bv.x - smN[0]) * siN[0];
        bv.y = __expf(bv.y - smN[1]) * siN[1];
        bv.z = __expf(bv.z - smN[2]) * siN[2];
        bv.w = __expf(bv.w - smN[3]) * siN[3];
      }
      *(float4*)&Bs[kk][c4] = bv;
    } else {
      int r = t >> 2, c4 = (t & 3) << 2;
      float4 bv = *(const float4*)&B[(long)(n0 + r) * ldb + kt + c4];
      if (EXPB) {
        bv.x = __expf(bv.x - smT) * siT;
        bv.y = __expf(bv.y - smT) * siT;
        bv.z = __expf(bv.z - smT) * siT;
        bv.w = __expf(bv.w - smT) * siT;
      }
      Bs[c4 + 0][r] = bv.x; Bs[c4 + 1][r] = bv.y; Bs[c4 + 2][r] = bv.z; Bs[c4 + 3][r] = bv.w;
    }
    __syncthreads();
    #pragma unroll
    for (int kk = 0; kk < 16; ++kk) {
      float4 av = *(float4*)&As[kk][ty << 2];
      float4 bv = *(float4*)&Bs[kk][tx << 2];
      float a4[4] = {av.x, av.y, av.z, av.w};
      float b4[4] = {bv.x, bv.y, bv.z, bv.w};
      #pragma unroll
      for (int i = 0; i < 4; ++i)
        #pragma unroll
        for (int j = 0; j < 4; ++j) acc[i][j] = fmaf(a4[i], b4[j], acc[i][j]);
    }
  }
  // ---- epilogue
  #pragma unroll
  for (int i = 0; i < 4; ++i) {
    int m = m0 + (ty << 2) + i;
    float bsv = BIAS ? bias[m] : 0.0f;
    #pragma unroll
    for (int j = 0; j < 4; ++j) {
      int n = n0 + (tx << 2) + j;
      if (ATOMIC) {
        atomicAdd(&C[(long)m * ldc + n], acc[i][j]);
      } else {
        float v = acc[i][j] + bsv;
        if (RESID) v += residb[(long)m * ldc + n];
        C[(long)m * ldc + n] = v;
      }
    }
  }
}

extern "C" void kernel_launch(void* const* d_in, const int* in_sizes, int n_in,
                              void* d_out, int out_size, void* d_ws, size_t ws_size,
                              hipStream_t stream) {
  const float* x1 = (const float*)d_in[0];
  const float* x2 = (const float*)d_in[1];
  const float* bn_pre = (const float*)d_in[2];
  const float* w_pre = (const float*)d_in[3];
  const float* b_pre = (const float*)d_in[4];
  const float* w_post = (const float*)d_in[5];
  const float* b_post = (const float*)d_in[6];
  const float* bn_post = (const float*)d_in[7];
  float* out = (float*)d_out;
  float* ws = (float*)d_ws;

  float* WPRE = ws + OFF_WPRE;
  float* BPRE = ws + OFF_BPRE;
  float* WPOST = ws + OFF_WPOST;
  float* BPOST = ws + OFF_BPOST;
  float* F1 = ws + OFF_F1;
  float* F2 = ws + OFF_F2;
  float* ET = ws + OFF_ET;
  float* M1 = ws + OFF_M1;
  float* M2 = ws + OFF_M2;
  float* A1 = ws + OFF_A1;
  float* A2 = ws + OFF_A2;
  float* Y1 = ws + OFF_Y1;
  float* Y2 = ws + OFF_Y2;
  float* RMX = ws + OFF_RMX;
  float* RINV = ws + OFF_RINV;
  float* CMX = ws + OFF_CMX;
  float* CINV = ws + OFF_CINV;
  float* ESP = ws + OFF_ESP;

  const long sX = (long)NC * HW_N;       // 256*2304 per batch
  const long sF = (long)NC * HW_N;
  const long sCI = (long)NCI * HW_N;     // 128*2304
  const long sE = (long)HW_N * HW_N;

  hipMemsetAsync(ET, 0, (size_t)NB * 128 * 128 * sizeof(float), stream);
  fold_pre<<<512, 256, 0, stream>>>(bn_pre, w_pre, b_pre, WPRE, BPRE);
  fold_post<<<512, 128, 0, stream>>>(bn_post, w_post, b_post, WPOST, BPOST);

  // pre GEMMs: F1 = Wc0 @ x1 + b0 ; F2 = Wc1 @ x2 + b1
  gemm64<false, false, false, true, false, false><<<dim3(36, 4, NB), 256, 0, stream>>>(
      WPRE, 256, 0, x1, HW_N, sX, F1, HW_N, sF, 256, 1, 256,
      BPRE, nullptr, nullptr, 0, nullptr, 0);
  gemm64<false, false, false, true, false, false><<<dim3(36, 4, NB), 256, 0, stream>>>(
      WPRE + 256 * 256, 256, 0, x2, HW_N, sX, F2, HW_N, sF, 256, 1, 256,
      BPRE + 256, nullptr, nullptr, 0, nullptr, 0);

  // e_time: Et[c][d] = sum_n th[c,n] ph[d,n]  (NT, K-split 8, atomic)
  gemm64<false, true, false, false, false, true><<<dim3(2, 2, NB * 8), 256, 0, stream>>>(
      F1 + (long)128 * HW_N, HW_N, sF, F2 + (long)128 * HW_N, HW_N, sF,
      ET, 128, 16384, HW_N, 8, 288, nullptr, nullptr, nullptr, 0, nullptr, 0);

  et_softmax<<<NB, 128, 0, stream>>>(ET, M1, M2);

  // A1 = M1 @ g11 ; A2 = M2 @ g21
  gemm64<false, false, false, false, false, false><<<dim3(36, 2, NB), 256, 0, stream>>>(
      M1, 128, 16384, F1, HW_N, sF, A1, HW_N, sCI, 128, 1, 128,
      nullptr, nullptr, nullptr, 0, nullptr, 0);
  gemm64<false, false, false, false, false, false><<<dim3(36, 2, NB), 256, 0, stream>>>(
      M2, 128, 16384, F2, HW_N, sF, A2, HW_N, sCI, 128, 1, 128,
      nullptr, nullptr, nullptr, 0, nullptr, 0);

  // E[n][m] = sum_c th[c,n] ph[c,m]  (A is [K][M] -> ATK)
  gemm64<true, false, false, false, false, false><<<dim3(36, 36, NB), 256, 0, stream>>>(
      F1 + (long)128 * HW_N, HW_N, sF, F2 + (long)128 * HW_N, HW_N, sF,
      ESP, HW_N, sE, 128, 1, 128, nullptr, nullptr, nullptr, 0, nullptr, 0);

  row_stats<<<dim3(HW_N, NB), 256, 0, stream>>>(ESP, RMX, RINV);
  col_stats<<<dim3(36, NB), 256, 0, stream>>>(ESP, CMX, CINV);

  // y1 = A1 @ colsoftmax(E)   (NN + exp on B, stats = col)
  gemm64<false, false, true, false, false, false><<<dim3(36, 2, NB), 256, 0, stream>>>(
      A1, HW_N, sCI, ESP, HW_N, sE, Y1, HW_N, sCI, HW_N, 1, HW_N,
      nullptr, CMX, CINV, HW_N, nullptr, 0);
  // y2 = A2 @ rowsoftmax(E)^T (NT + exp on B, stats = row)
  gemm64<false, true, true, false, false, false><<<dim3(36, 2, NB), 256, 0, stream>>>(
      A2, HW_N, sCI, ESP, HW_N, sE, Y2, HW_N, sCI, HW_N, 1, HW_N,
      nullptr, RMX, RINV, HW_N, nullptr, 0);

  // post: out_i = x_i + Wpost[i] @ y_i + bias_i
  gemm64<false, false, false, true, true, false><<<dim3(36, 4, NB), 256, 0, stream>>>(
      WPOST, 128, 0, Y1, HW_N, sCI, out, HW_N, sX, 128, 1, 128,
      BPOST, nullptr, nullptr, 0, x1, sX);
  gemm64<false, false, false, true, true, false><<<dim3(36, 4, NB), 256, 0, stream>>>(
      WPOST + 256 * 128, 128, 0, Y2, HW_N, sCI, out + (long)NB * NC * HW_N, HW_N, sX, 128, 1, 128,
      BPOST + 256, nullptr, nullptr, 0, x2, sX);
}

// Round 3
// 284.770 us; speedup vs baseline: 3.1232x; 3.1232x over previous
//
#include <hip/hip_runtime.h>
#include <hip/hip_bf16.h>

// SpatiotemporalAttention — bf16 MFMA pipeline.
// B=4, C=256, CI=128, N=48*48=2304.
//
// Precision plan:
//   split-bf16 (hi+lo, 3-term MFMA, fp32-quality): pre convs, e_time, e_space
//   plain bf16: A-gemms (ets@g), y-gemms (A@P), post convs
//   softmax(e_space) without max-subtraction: P = exp(E) stored bf16 (|E|<~45),
//   normalization folded into y-gemm epilogue as 1/colsum.
//
// All GEMM operands canonicalized K-contiguous: C[m,n] = sum_k A[m,k]*Bt[n,k].

#define N_PIX 2304
#define NB 4

typedef __attribute__((ext_vector_type(8))) short bf16x8;
typedef __attribute__((ext_vector_type(4))) float f32x4;

__device__ __forceinline__ short f2bf(float f) {
  unsigned u = __float_as_uint(f);
  unsigned r = (u + 0x7fffu + ((u >> 16) & 1u)) >> 16;
  return (short)r;
}
__device__ __forceinline__ float bf2f(short s) {
  return __uint_as_float(((unsigned)(unsigned short)s) << 16);
}
__device__ __forceinline__ int swz(int row, int kc) {
  return kc ^ ((row ^ (row >> 3)) & 7);
}
__device__ __forceinline__ unsigned pk2(short a, short b) {
  return (unsigned)(unsigned short)a | ((unsigned)(unsigned short)b << 16);
}

// ---------------- workspace layout (byte offsets) ----------------
// BPRE   f32[512]            @ 0
// BPOST  f32[512]            @ 2048
// CS     f32[4*2304]         @ 4096      (colsum of P = rowsum of PT)
// RS     f32[4*2304]         @ 40960     (rowsum of P = colsum of PT, atomic)
// ET     f32[4*128*128]      @ 77824
// WPREH  bf16[2*256*256]     @ 339968
// WPREL  bf16[2*256*256]     @ 602112
// WPOSTB bf16[2*256*128]     @ 864256
// MB     bf16[2*4*128*128]   @ 995328    (M1 then M2)
// XTH    bf16[2*4*2304*256]  @ 1257472   (x^T hi)
// XTL    bf16[2*4*2304*256]  @ 10694656
// FB     bf16[2*4*128*2304]  @ 20131840  (theta/phi rows only, natural)
// FLO    bf16[2*4*128*2304]  @ 24850432
// FTB    bf16[2*4*2304*256]  @ 29569024  (F^T, all rows)
// FTLO   bf16[2*4*2304*128]  @ 39006208  (F^T lo, theta/phi cols only)
// AB     bf16[2*4*128*2304]  @ 43724800
// YT     bf16[2*4*2304*128]  @ 48443392  (y^T)
// PT     bf16[4*2304*2304]   @ 53161984  (PT[a][b] = exp(E[b][a]))
// total ~95.6 MB

struct GArgs {
  const short *a0, *a1, *al0, *al1;
  const short *b0, *b1, *bl0, *bl1;
  long sa, sb, sal, sbl;
  int lda, ldb, lal, lbl;
  int K, ksplit, kchunk;
  int bt0, bt1;                       // B stored [K][N] -> transpose-stage
  void *o0, *o1; long so;
  void *p0, *p1; long sp;
  void *q0, *q1; long sq;
  void *u0, *u1; long su;
  const float *aux0, *aux1; long saux;  // bias (EPI0/5) or col-sums (EPI4)
  const float *res0, *res1; long sres;  // residual (EPI5)
};

// EPI: 0=pre(F_b/F_lo/FT_b/FT_lo + bias)  1=e_time(atomic f32)
//      2=ESP(exp -> PT)  3=A(bf16 natural)  4=y(scale 1/S -> yT)  5=post(f32+bias+resid)
template <int EPI, int SPLIT>
__global__ __launch_bounds__(256) void mgemm(GArgs g) {
  int z = blockIdx.z;
  int pb = z / g.ksplit, ks = z - pb * g.ksplit;
  int sel = pb >> 2, batch = pb & 3;
  const short* A = (sel ? g.a1 : g.a0) + (long)batch * g.sa;
  const short* B = (sel ? g.b1 : g.b0) + (long)batch * g.sb;
  const short* Al = nullptr; const short* Bl = nullptr;
  if (SPLIT) {
    Al = (sel ? g.al1 : g.al0) + (long)batch * g.sal;
    Bl = (sel ? g.bl1 : g.bl0) + (long)batch * g.sbl;
  }
  int bt = sel ? g.bt1 : g.bt0;
  int k0 = ks * g.kchunk, k1 = k0 + g.kchunk;
  int m0 = blockIdx.y << 7, n0 = blockIdx.x << 7;

  __shared__ short As[128 * 64];
  __shared__ short Bs[128 * 64];
  __shared__ short Als[SPLIT ? 128 * 64 : 8];
  __shared__ short Bls[SPLIT ? 128 * 64 : 8];

  int t = threadIdx.x;
  int lane = t & 63, wid = t >> 6;
  int wm = (wid >> 1) << 6, wn = (wid & 1) << 6;
  int l15 = lane & 15, lg = lane >> 4;

  f32x4 acc[4][4];
  #pragma unroll
  for (int i = 0; i < 4; ++i)
    #pragma unroll
    for (int j = 0; j < 4; ++j) acc[i][j] = (f32x4){0.f, 0.f, 0.f, 0.f};

  for (int kt = k0; kt < k1; kt += 64) {
    __syncthreads();
    #pragma unroll
    for (int i = 0; i < 4; ++i) {
      int ch = t + (i << 8);
      int row = ch >> 3, kc = ch & 7;
      int di = (row << 6) + (swz(row, kc) << 3);
      *(bf16x8*)&As[di] = *(const bf16x8*)&A[(long)(m0 + row) * g.lda + kt + (kc << 3)];
      if (SPLIT)
        *(bf16x8*)&Als[di] = *(const bf16x8*)&Al[(long)(m0 + row) * g.lal + kt + (kc << 3)];
    }
    if (!bt) {
      #pragma unroll
      for (int i = 0; i < 4; ++i) {
        int ch = t + (i << 8);
        int row = ch >> 3, kc = ch & 7;
        int di = (row << 6) + (swz(row, kc) << 3);
        *(bf16x8*)&Bs[di] = *(const bf16x8*)&B[(long)(n0 + row) * g.ldb + kt + (kc << 3)];
        if (SPLIT)
          *(bf16x8*)&Bls[di] = *(const bf16x8*)&Bl[(long)(n0 + row) * g.lbl + kt + (kc << 3)];
      }
    } else {
      // B stored [K][N']: coalesced row reads, transposed scatter into LDS
      #pragma unroll
      for (int i = 0; i < 4; ++i) {
        int ch = t + (i << 8);
        int nc = ch & 15, kk = ch >> 4;
        bf16x8 ld = *(const bf16x8*)&B[(long)(kt + kk) * g.ldb + n0 + (nc << 3)];
        int kc = kk >> 3, w = kk & 7;
        #pragma unroll
        for (int e = 0; e < 8; ++e) {
          int rn = (nc << 3) + e;
          Bs[(rn << 6) + (swz(rn, kc) << 3) + w] = ld[e];
        }
      }
    }
    __syncthreads();
    #pragma unroll
    for (int ksub = 0; ksub < 2; ++ksub) {
      int kb = (ksub << 2) + lg;
      bf16x8 ah[4], bh[4], alv[4], blv[4];
      #pragma unroll
      for (int i = 0; i < 4; ++i) {
        int ra = wm + (i << 4) + l15;
        int rb = wn + (i << 4) + l15;
        ah[i] = *(const bf16x8*)&As[(ra << 6) + (swz(ra, kb) << 3)];
        bh[i] = *(const bf16x8*)&Bs[(rb << 6) + (swz(rb, kb) << 3)];
        if (SPLIT) {
          alv[i] = *(const bf16x8*)&Als[(ra << 6) + (swz(ra, kb) << 3)];
          blv[i] = *(const bf16x8*)&Bls[(rb << 6) + (swz(rb, kb) << 3)];
        }
      }
      #pragma unroll
      for (int i = 0; i < 4; ++i)
        #pragma unroll
        for (int j = 0; j < 4; ++j) {
          if (SPLIT) {
            acc[i][j] = __builtin_amdgcn_mfma_f32_16x16x32_bf16(alv[i], bh[j], acc[i][j], 0, 0, 0);
            acc[i][j] = __builtin_amdgcn_mfma_f32_16x16x32_bf16(ah[i], blv[j], acc[i][j], 0, 0, 0);
          }
          acc[i][j] = __builtin_amdgcn_mfma_f32_16x16x32_bf16(ah[i], bh[j], acc[i][j], 0, 0, 0);
        }
    }
  }

  // ---------------- epilogue ----------------
  #pragma unroll
  for (int j = 0; j < 4; ++j) {
    int col = n0 + wn + (j << 4) + l15;
    float sc = 1.f;
    if (EPI == 4) {
      const float* S = (sel ? g.aux1 : g.aux0) + (long)batch * g.saux;
      sc = 1.0f / S[col];
    }
    #pragma unroll
    for (int i = 0; i < 4; ++i) {
      int row0 = m0 + wm + (i << 4) + (lg << 2);
      if (EPI == 0) {
        const float* bias = (sel ? g.aux1 : g.aux0);
        short* FTB_ = (short*)(sel ? g.q1 : g.q0) + (long)batch * g.sq;
        float v[4]; short hh[4];
        #pragma unroll
        for (int r = 0; r < 4; ++r) { v[r] = acc[i][j][r] + bias[row0 + r]; hh[r] = f2bf(v[r]); }
        uint2 pk; pk.x = pk2(hh[0], hh[1]); pk.y = pk2(hh[2], hh[3]);
        *(uint2*)&FTB_[(long)col * 256 + row0] = pk;
        if (row0 >= 128) {
          short* FB_  = (short*)(sel ? g.o1 : g.o0) + (long)batch * g.so;
          short* FLO_ = (short*)(sel ? g.p1 : g.p0) + (long)batch * g.sp;
          short* FTL_ = (short*)(sel ? g.u1 : g.u0) + (long)batch * g.su;
          short ll[4];
          #pragma unroll
          for (int r = 0; r < 4; ++r) {
            ll[r] = f2bf(v[r] - bf2f(hh[r]));
            FB_[(long)(row0 - 128 + r) * N_PIX + col] = hh[r];
            FLO_[(long)(row0 - 128 + r) * N_PIX + col] = ll[r];
          }
          uint2 pl; pl.x = pk2(ll[0], ll[1]); pl.y = pk2(ll[2], ll[3]);
          *(uint2*)&FTL_[(long)col * 128 + (row0 - 128)] = pl;
        }
      } else if (EPI == 1) {
        float* ET_ = (float*)g.o0 + (long)batch * g.so;
        #pragma unroll
        for (int r = 0; r < 4; ++r) atomicAdd(&ET_[(long)(row0 + r) * 128 + col], acc[i][j][r]);
      } else if (EPI == 2) {
        short* PT_ = (short*)g.o0 + (long)batch * g.so;
        short hh[4];
        #pragma unroll
        for (int r = 0; r < 4; ++r) hh[r] = f2bf(__expf(acc[i][j][r]));
        uint2 pk; pk.x = pk2(hh[0], hh[1]); pk.y = pk2(hh[2], hh[3]);
        *(uint2*)&PT_[(long)col * N_PIX + row0] = pk;
      } else if (EPI == 3) {
        short* AB_ = (short*)(sel ? g.o1 : g.o0) + (long)batch * g.so;
        #pragma unroll
        for (int r = 0; r < 4; ++r) AB_[(long)(row0 + r) * N_PIX + col] = f2bf(acc[i][j][r]);
      } else if (EPI == 4) {
        short* YT_ = (short*)(sel ? g.o1 : g.o0) + (long)batch * g.so;
        short hh[4];
        #pragma unroll
        for (int r = 0; r < 4; ++r) hh[r] = f2bf(acc[i][j][r] * sc);
        uint2 pk; pk.x = pk2(hh[0], hh[1]); pk.y = pk2(hh[2], hh[3]);
        *(uint2*)&YT_[(long)col * 128 + row0] = pk;
      } else {
        float* O_ = (float*)(sel ? g.o1 : g.o0) + (long)batch * g.so;
        const float* bias = (sel ? g.aux1 : g.aux0);
        const float* R_ = (sel ? g.res1 : g.res0) + (long)batch * g.sres;
        #pragma unroll
        for (int r = 0; r < 4; ++r)
          O_[(long)(row0 + r) * N_PIX + col] =
              acc[i][j][r] + bias[row0 + r] + R_[(long)(row0 + r) * N_PIX + col];
      }
    }
  }
}

// ---------------- helper kernels ----------------

__global__ __launch_bounds__(256) void xcast(const float* __restrict__ x1,
                                             const float* __restrict__ x2,
                                             short* __restrict__ XH, short* __restrict__ XL) {
  __shared__ float tile[32][33];
  int z = blockIdx.z; int sel = z >> 2, b = z & 3;
  const float* X = (sel ? x2 : x1) + (long)b * 256 * N_PIX;
  long obase = ((long)(sel * 4 + b)) * N_PIX * 256;
  int n0 = blockIdx.x << 5, c0 = blockIdx.y << 5;
  int tx = threadIdx.x & 31, ty = threadIdx.x >> 5;
  #pragma unroll
  for (int i = 0; i < 4; ++i)
    tile[ty + (i << 3)][tx] = X[(long)(c0 + ty + (i << 3)) * N_PIX + n0 + tx];
  __syncthreads();
  #pragma unroll
  for (int i = 0; i < 4; ++i) {
    int n = n0 + ty + (i << 3);
    float v = tile[tx][ty + (i << 3)];
    short h = f2bf(v);
    XH[obase + (long)n * 256 + c0 + tx] = h;
    XL[obase + (long)n * 256 + c0 + tx] = f2bf(v - bf2f(h));
  }
}

__global__ __launch_bounds__(256) void fold_pre(const float* __restrict__ bn,
                                                const float* __restrict__ w,
                                                const float* __restrict__ b,
                                                short* __restrict__ WH, short* __restrict__ WL,
                                                float* __restrict__ Bc) {
  int blk = blockIdx.x;
  int xsel = blk >> 8, row = blk & 255;
  int i = (row < 128) ? xsel : (2 + xsel);
  int o = row & 127;
  int c = threadIdx.x;
  const float* bni = bn + i * 1024;
  float gm = bni[c], be = bni[256 + c], mn = bni[512 + c], vr = bni[768 + c];
  float s = gm * rsqrtf(vr + 1e-5f);
  float tb = be - mn * s;
  float wv = w[(i * 128 + o) * 256 + c];
  float val = wv * s;
  short h = f2bf(val);
  long idx = (long)(xsel * 256 + row) * 256 + c;
  WH[idx] = h;
  WL[idx] = f2bf(val - bf2f(h));
  __shared__ float red[256];
  red[c] = wv * tb;
  __syncthreads();
  for (int off = 128; off > 0; off >>= 1) {
    if (c < off) red[c] += red[c + off];
    __syncthreads();
  }
  if (c == 0) Bc[xsel * 256 + row] = b[i * 128 + o] + red[0];
}

__global__ __launch_bounds__(128) void fold_post(const float* __restrict__ bn,
                                                 const float* __restrict__ w,
                                                 const float* __restrict__ b,
                                                 short* __restrict__ WB, float* __restrict__ Bc) {
  int blk = blockIdx.x;
  int i = blk >> 8, o = blk & 255;
  const float* bni = bn + i * 1024;
  float s = bni[o] * rsqrtf(bni[768 + o] + 1e-5f);
  int c = threadIdx.x;
  long idx = (long)(i * 256 + o) * 128 + c;
  WB[idx] = f2bf(w[idx] * s);
  if (c == 0) Bc[i * 256 + o] = b[i * 256 + o] * s + bni[256 + o] - bni[512 + o] * s;
}

// time-energy softmaxes: M1[c][d] = colsoftmax (et2s), M2[c][d] = rowsoftmax (et1s)
__global__ __launch_bounds__(128) void et_softmax(const float* __restrict__ Et,
                                                  short* __restrict__ MB) {
  __shared__ float Es[128 * 128];
  int b = blockIdx.x, t = threadIdx.x;
  const float* E = Et + (long)b * 16384;
  for (int i = t; i < 16384; i += 128) Es[i] = E[i];
  __syncthreads();
  short* M1 = MB + (long)b * 16384;
  short* M2 = MB + (long)(4 + b) * 16384;
  float rm = -1e30f;
  for (int j = 0; j < 128; ++j) rm = fmaxf(rm, Es[t * 128 + j]);
  float rs = 0.f;
  for (int j = 0; j < 128; ++j) rs += __expf(Es[t * 128 + j] - rm);
  float ri = 1.0f / rs;
  for (int j = 0; j < 128; ++j) M2[t * 128 + j] = f2bf(__expf(Es[t * 128 + j] - rm) * ri);
  float cm = -1e30f;
  for (int d = 0; d < 128; ++d) cm = fmaxf(cm, Es[d * 128 + t]);
  float cs = 0.f;
  for (int d = 0; d < 128; ++d) cs += __expf(Es[d * 128 + t] - cm);
  float ci = 1.0f / cs;
  for (int d = 0; d < 128; ++d) M1[t * 128 + d] = f2bf(__expf(Es[d * 128 + t] - cm) * ci);
}

__global__ __launch_bounds__(256) void rowsum(const short* __restrict__ P, float* __restrict__ S) {
  long row = blockIdx.x;
  const short* p = P + row * N_PIX;
  int t = threadIdx.x;
  float s = 0.f;
  for (int c = t; c < 288; c += 256) {
    bf16x8 v = *(const bf16x8*)&p[c << 3];
    #pragma unroll
    for (int e = 0; e < 8; ++e) s += bf2f(v[e]);
  }
  #pragma unroll
  for (int off = 32; off > 0; off >>= 1) s += __shfl_down(s, off, 64);
  __shared__ float red[4];
  if ((t & 63) == 0) red[t >> 6] = s;
  __syncthreads();
  if (t == 0) S[row] = red[0] + red[1] + red[2] + red[3];
}

__global__ __launch_bounds__(256) void colsum(const short* __restrict__ PT, float* __restrict__ S) {
  int b = blockIdx.z;
  int c = (blockIdx.x << 8) + threadIdx.x;
  int r0 = blockIdx.y << 7;
  const short* p = PT + (long)b * N_PIX * N_PIX + (long)r0 * N_PIX + c;
  float s = 0.f;
  for (int r = 0; r < 128; ++r) s += bf2f(p[(long)r * N_PIX]);
  atomicAdd(&S[b * N_PIX + c], s);
}

extern "C" void kernel_launch(void* const* d_in, const int* in_sizes, int n_in,
                              void* d_out, int out_size, void* d_ws, size_t ws_size,
                              hipStream_t stream) {
  const float* x1 = (const float*)d_in[0];
  const float* x2 = (const float*)d_in[1];
  const float* bn_pre = (const float*)d_in[2];
  const float* w_pre = (const float*)d_in[3];
  const float* b_pre = (const float*)d_in[4];
  const float* w_post = (const float*)d_in[5];
  const float* b_post = (const float*)d_in[6];
  const float* bn_post = (const float*)d_in[7];
  float* out = (float*)d_out;

  char* W = (char*)d_ws;
  float* BPRE  = (float*)(W + 0);
  float* BPOST = (float*)(W + 2048);
  float* CS    = (float*)(W + 4096);
  float* RS    = (float*)(W + 40960);
  float* ET    = (float*)(W + 77824);
  short* WPREH = (short*)(W + 339968);
  short* WPREL = (short*)(W + 602112);
  short* WPOSTB= (short*)(W + 864256);
  short* MB    = (short*)(W + 995328);
  short* XTH   = (short*)(W + 1257472);
  short* XTL   = (short*)(W + 10694656);
  short* FB    = (short*)(W + 20131840);
  short* FLO   = (short*)(W + 24850432);
  short* FTB   = (short*)(W + 29569024);
  short* FTLO  = (short*)(W + 39006208);
  short* AB    = (short*)(W + 43724800);
  short* YT    = (short*)(W + 48443392);
  short* PT    = (short*)(W + 53161984);

  hipMemsetAsync(ET, 0, 262144, stream);
  hipMemsetAsync(RS, 0, 36864, stream);
  xcast<<<dim3(72, 8, 8), 256, 0, stream>>>(x1, x2, XTH, XTL);
  fold_pre<<<512, 256, 0, stream>>>(bn_pre, w_pre, b_pre, WPREH, WPREL, BPRE);
  fold_post<<<512, 128, 0, stream>>>(bn_post, w_post, b_post, WPOSTB, BPOST);

  { GArgs g{};  // pre convs (split): F = Wc @ x  -> FB/FLO (theta,phi), FTB/FTLO
    g.a0 = WPREH; g.a1 = WPREH + 65536; g.al0 = WPREL; g.al1 = WPREL + 65536;
    g.sa = 0; g.sal = 0; g.lda = 256; g.lal = 256;
    g.b0 = XTH; g.b1 = XTH + 4L * 2304 * 256; g.bl0 = XTL; g.bl1 = XTL + 4L * 2304 * 256;
    g.sb = 2304L * 256; g.sbl = 2304L * 256; g.ldb = 256; g.lbl = 256;
    g.K = 256; g.ksplit = 1; g.kchunk = 256; g.bt0 = 0; g.bt1 = 0;
    g.o0 = FB; g.o1 = FB + 4L * 128 * 2304; g.so = 128L * 2304;
    g.p0 = FLO; g.p1 = FLO + 4L * 128 * 2304; g.sp = 128L * 2304;
    g.q0 = FTB; g.q1 = FTB + 4L * 2304 * 256; g.sq = 2304L * 256;
    g.u0 = FTLO; g.u1 = FTLO + 4L * 2304 * 128; g.su = 2304L * 128;
    g.aux0 = BPRE; g.aux1 = BPRE + 256; g.saux = 0;
    mgemm<0, 1><<<dim3(18, 2, 8), 256, 0, stream>>>(g); }

  { GArgs g{};  // e_time (split, K-split atomic): Et[c][d] = sum_n th[c,n] ph[d,n]
    g.a0 = g.a1 = FB; g.al0 = g.al1 = FLO;
    g.sa = g.sal = 128L * 2304; g.lda = g.lal = 2304;
    g.b0 = g.b1 = FB + 4L * 128 * 2304; g.bl0 = g.bl1 = FLO + 4L * 128 * 2304;
    g.sb = g.sbl = 128L * 2304; g.ldb = g.lbl = 2304;
    g.K = 2304; g.ksplit = 12; g.kchunk = 192; g.bt0 = 0; g.bt1 = 0;
    g.o0 = g.o1 = ET; g.so = 16384;
    mgemm<1, 1><<<dim3(1, 1, 48), 256, 0, stream>>>(g); }

  et_softmax<<<4, 128, 0, stream>>>(ET, MB);

  { GArgs g{};  // e_space (split): PT[m][n] = exp(E[n][m]), E[n][m] = sum_c th[c,n] ph[c,m]
    g.a0 = g.a1 = FTB + 128; g.al0 = g.al1 = FTLO;
    g.sa = 2304L * 256; g.sal = 2304L * 128; g.lda = 256; g.lal = 128;
    g.b0 = g.b1 = FTB + 4L * 2304 * 256 + 128; g.bl0 = g.bl1 = FTLO + 4L * 2304 * 128;
    g.sb = 2304L * 256; g.sbl = 2304L * 128; g.ldb = 256; g.lbl = 128;
    g.K = 128; g.ksplit = 1; g.kchunk = 128; g.bt0 = 0; g.bt1 = 0;
    g.o0 = g.o1 = PT; g.so = (long)2304 * 2304;
    mgemm<2, 1><<<dim3(18, 18, 4), 256, 0, stream>>>(g); }

  rowsum<<<9216, 256, 0, stream>>>(PT, CS);              // CS[m] = sum_n exp(E[n,m])
  colsum<<<dim3(9, 18, 4), 256, 0, stream>>>(PT, RS);    // RS[m] = sum_n exp(E[m,n])

  { GArgs g{};  // A-gemms: A1 = M1 @ g11, A2 = M2 @ g21  (B = FTB cols 0..127 = g^T)
    g.a0 = MB; g.a1 = MB + 4 * 16384; g.sa = 16384; g.lda = 128;
    g.b0 = FTB; g.b1 = FTB + 4L * 2304 * 256; g.sb = 2304L * 256; g.ldb = 256;
    g.K = 128; g.ksplit = 1; g.kchunk = 128; g.bt0 = 0; g.bt1 = 0;
    g.o0 = AB; g.o1 = AB + 4L * 128 * 2304; g.so = 128L * 2304;
    mgemm<3, 0><<<dim3(18, 1, 8), 256, 0, stream>>>(g); }

  { GArgs g{};  // y-gemms: y1 = A1 @ PT^T(K-contig), y2 = A2 @ PT(transpose-stage); scale 1/S
    g.a0 = AB; g.a1 = AB + 4L * 128 * 2304; g.sa = 128L * 2304; g.lda = 2304;
    g.b0 = g.b1 = PT; g.sb = (long)2304 * 2304; g.ldb = 2304;
    g.K = 2304; g.ksplit = 1; g.kchunk = 2304; g.bt0 = 0; g.bt1 = 1;
    g.o0 = YT; g.o1 = YT + 4L * 2304 * 128; g.so = 2304L * 128;
    g.aux0 = CS; g.aux1 = RS; g.saux = 2304;
    mgemm<4, 0><<<dim3(18, 1, 8), 256, 0, stream>>>(g); }

  { GArgs g{};  // post convs: out_i = x_i + Wpost_i @ y_i + bias
    g.a0 = WPOSTB; g.a1 = WPOSTB + 32768; g.sa = 0; g.lda = 128;
    g.b0 = YT; g.b1 = YT + 4L * 2304 * 128; g.sb = 2304L * 128; g.ldb = 128;
    g.K = 128; g.ksplit = 1; g.kchunk = 128; g.bt0 = 0; g.bt1 = 0;
    g.o0 = out; g.o1 = out + 4L * 256 * 2304; g.so = 256L * 2304;
    g.aux0 = BPOST; g.aux1 = BPOST + 256; g.saux = 0;
    g.res0 = x1; g.res1 = x2; g.sres = 256L * 2304;
    mgemm<5, 0><<<dim3(18, 2, 8), 256, 0, stream>>>(g); }
}